// Round 1
// baseline (2476.824 us; speedup 1.0000x reference)
//
#include <hip/hip_runtime.h>
#include <hip/hip_bf16.h>
#include <cstdint>

#define BT 2048
#define HS 2048
#define HT 4096
#define VOCAB 32000
#define IGNORE_IDX (-100)

#define BM 128
#define BN 128
#define BK 32
#define LDK (BK + 8)   // padded LDS stride: 40 elems = 80 B -> 2-way conflicts only (free)

typedef __bf16 bf16x8 __attribute__((ext_vector_type(8)));
typedef float  f32x4  __attribute__((ext_vector_type(4)));

__device__ __forceinline__ unsigned short f2bf(float f) {
    unsigned int u = __float_as_uint(f);
    u += 0x7FFFu + ((u >> 16) & 1u);   // RNE
    return (unsigned short)(u >> 16);
}
__device__ __forceinline__ float bf2f(unsigned int h) {
    return __uint_as_float(h << 16);
}
__device__ __forceinline__ void unpack8(const unsigned short* p, float* f) {
    const uint4 u = *(const uint4*)p;
    f[0] = bf2f(u.x & 0xFFFFu); f[1] = bf2f(u.x >> 16);
    f[2] = bf2f(u.y & 0xFFFFu); f[3] = bf2f(u.y >> 16);
    f[4] = bf2f(u.z & 0xFFFFu); f[5] = bf2f(u.z >> 16);
    f[6] = bf2f(u.w & 0xFFFFu); f[7] = bf2f(u.w >> 16);
}

// C[m][n] = sum_k A[m][k] * B[n][k]; A: BT x K fp32, B: VOCAB x K fp32, C: BT x VOCAB bf16 bits
__global__ __launch_bounds__(256) void gemm_bt_kernel(
    const float* __restrict__ A,
    const float* __restrict__ B,
    unsigned short* __restrict__ C,
    const int K)
{
    __shared__ unsigned short As[BM][LDK];
    __shared__ unsigned short Bs[BN][LDK];

    const int row0 = blockIdx.x * BM;   // x fastest -> consecutive blocks share the B tile (L2)
    const int col0 = blockIdx.y * BN;
    const int tid  = threadIdx.x;
    const int wave = tid >> 6;
    const int lane = tid & 63;
    const int q    = lane >> 4;
    const int l15  = lane & 15;
    const int wm   = (wave & 1) * 64;
    const int wn   = (wave >> 1) * 64;

    f32x4 acc[4][4];
#pragma unroll
    for (int i = 0; i < 4; ++i)
#pragma unroll
        for (int j = 0; j < 4; ++j)
            acc[i][j] = (f32x4){0.f, 0.f, 0.f, 0.f};

    const int rbase = tid >> 3;        // 0..31
    const int cbase = (tid & 7) * 4;   // 0,4,...,28

    for (int kt = 0; kt < K; kt += BK) {
#pragma unroll
        for (int u = 0; u < 4; ++u) {
            const int r = rbase + u * 32;
            const float4 av = *(const float4*)(A + (size_t)(row0 + r) * K + kt + cbase);
            const float4 bv = *(const float4*)(B + (size_t)(col0 + r) * K + kt + cbase);
            ushort4 a16, b16;
            a16.x = f2bf(av.x); a16.y = f2bf(av.y); a16.z = f2bf(av.z); a16.w = f2bf(av.w);
            b16.x = f2bf(bv.x); b16.y = f2bf(bv.y); b16.z = f2bf(bv.z); b16.w = f2bf(bv.w);
            *(ushort4*)(&As[r][cbase]) = a16;
            *(ushort4*)(&Bs[r][cbase]) = b16;
        }
        __syncthreads();

        bf16x8 af[4], bfr[4];
#pragma unroll
        for (int i = 0; i < 4; ++i)
            af[i] = *(const bf16x8*)(&As[wm + i * 16 + l15][q * 8]);
#pragma unroll
        for (int j = 0; j < 4; ++j)
            bfr[j] = *(const bf16x8*)(&Bs[wn + j * 16 + l15][q * 8]);

#pragma unroll
        for (int i = 0; i < 4; ++i)
#pragma unroll
            for (int j = 0; j < 4; ++j)
                acc[i][j] = __builtin_amdgcn_mfma_f32_16x16x32_bf16(af[i], bfr[j], acc[i][j], 0, 0, 0);
        __syncthreads();
    }

    // C/D layout: col = lane&15, row = quad*4 + reg  [measured m89/m91]
#pragma unroll
    for (int i = 0; i < 4; ++i) {
        const int rr = row0 + wm + i * 16 + q * 4;
#pragma unroll
        for (int j = 0; j < 4; ++j) {
            const int cc = col0 + wn + j * 16 + l15;
#pragma unroll
            for (int r = 0; r < 4; ++r)
                C[(size_t)(rr + r) * VOCAB + cc] = f2bf(acc[i][j][r]);
        }
    }
}

// one block per row: online logsumexp for student+teacher, then JSD sum
__global__ __launch_bounds__(256) void jsd_row_kernel(
    const unsigned short* __restrict__ SL,
    const unsigned short* __restrict__ TL,
    float* __restrict__ row_out)
{
    const int row  = blockIdx.x;
    const int tid  = threadIdx.x;
    const int wave = tid >> 6;
    const int lane = tid & 63;
    const unsigned short* srow = SL + (size_t)row * VOCAB;
    const unsigned short* trow = TL + (size_t)row * VOCAB;

    __shared__ float red[4][4];
    __shared__ float lse_sh[2];

    float sm = -1e30f, sz = 0.f, tm = -1e30f, tz = 0.f;
    for (int v8 = tid; v8 < VOCAB / 8; v8 += 256) {
        float fs[8], ft[8];
        unpack8(srow + v8 * 8, fs);
        unpack8(trow + v8 * 8, ft);
        float lm = fs[0], lmt = ft[0];
#pragma unroll
        for (int k = 1; k < 8; ++k) { lm = fmaxf(lm, fs[k]); lmt = fmaxf(lmt, ft[k]); }
        float lz = 0.f, lzt = 0.f;
#pragma unroll
        for (int k = 0; k < 8; ++k) { lz += __expf(fs[k] - lm); lzt += __expf(ft[k] - lmt); }
        float nm = fmaxf(sm, lm);
        sz = sz * __expf(sm - nm) + lz * __expf(lm - nm);
        sm = nm;
        nm = fmaxf(tm, lmt);
        tz = tz * __expf(tm - nm) + lzt * __expf(lmt - nm);
        tm = nm;
    }
#pragma unroll
    for (int off = 32; off > 0; off >>= 1) {
        float m2 = __shfl_down(sm, off), z2 = __shfl_down(sz, off);
        float nm = fmaxf(sm, m2);
        sz = sz * __expf(sm - nm) + z2 * __expf(m2 - nm);
        sm = nm;
        m2 = __shfl_down(tm, off); z2 = __shfl_down(tz, off);
        nm = fmaxf(tm, m2);
        tz = tz * __expf(tm - nm) + z2 * __expf(m2 - nm);
        tm = nm;
    }
    if (lane == 0) { red[wave][0] = sm; red[wave][1] = sz; red[wave][2] = tm; red[wave][3] = tz; }
    __syncthreads();
    if (tid == 0) {
        float m = red[0][0], z = red[0][1];
        for (int w = 1; w < 4; ++w) {
            float m2 = red[w][0], z2 = red[w][1];
            float nm = fmaxf(m, m2);
            z = z * __expf(m - nm) + z2 * __expf(m2 - nm);
            m = nm;
        }
        lse_sh[0] = m + logf(z);
        m = red[0][2]; z = red[0][3];
        for (int w = 1; w < 4; ++w) {
            float m2 = red[w][2], z2 = red[w][3];
            float nm = fmaxf(m, m2);
            z = z * __expf(m - nm) + z2 * __expf(m2 - nm);
            m = nm;
        }
        lse_sh[1] = m + logf(z);
    }
    __syncthreads();
    const float slse = lse_sh[0], tlse = lse_sh[1];

    float accv = 0.f;
    for (int v8 = tid; v8 < VOCAB / 8; v8 += 256) {
        float fs[8], ft[8];
        unpack8(srow + v8 * 8, fs);
        unpack8(trow + v8 * 8, ft);
#pragma unroll
        for (int k = 0; k < 8; ++k) {
            const float sp = fs[k] - slse;   // log Q
            const float tp = ft[k] - tlse;   // log P
            const float Q = __expf(sp), P = __expf(tp);
            const float logM = __logf(0.5f * (P + Q) + 1e-38f);
            accv += P * (tp - logM) + Q * (sp - logM);
        }
    }
    accv *= 0.5f;   // beta = 0.5
#pragma unroll
    for (int off = 32; off > 0; off >>= 1) accv += __shfl_down(accv, off);
    if (lane == 0) red[wave][0] = accv;
    __syncthreads();
    if (tid == 0) row_out[row] = red[0][0] + red[1][0] + red[2][0] + red[3][0];
}

__global__ __launch_bounds__(256) void finalize_kernel(
    const float* __restrict__ row_sums,
    const int* __restrict__ labels,
    float* __restrict__ out)
{
    const int tid = threadIdx.x;
    float s = 0.f;
    int   c = 0;
    for (int r = tid; r < BT; r += 256) {
        if (labels[r] != IGNORE_IDX) { s += row_sums[r]; c += 1; }
    }
#pragma unroll
    for (int off = 32; off > 0; off >>= 1) {
        s += __shfl_down(s, off);
        c += __shfl_down(c, off);
    }
    __shared__ float ss[4];
    __shared__ int   cc[4];
    const int wave = tid >> 6, lane = tid & 63;
    if (lane == 0) { ss[wave] = s; cc[wave] = c; }
    __syncthreads();
    if (tid == 0) {
        const float S = ss[0] + ss[1] + ss[2] + ss[3];
        const int   C = cc[0] + cc[1] + cc[2] + cc[3];
        out[0] = S / (float)(C > 0 ? C : 1);
    }
}

extern "C" void kernel_launch(void* const* d_in, const int* in_sizes, int n_in,
                              void* d_out, int out_size, void* d_ws, size_t ws_size,
                              hipStream_t stream)
{
    const float* s_in = (const float*)d_in[0];
    const float* s_w  = (const float*)d_in[1];
    const float* t_in = (const float*)d_in[2];
    const float* t_w  = (const float*)d_in[3];
    const int*   lbl  = (const int*)d_in[4];
    float* out = (float*)d_out;

    unsigned short* s_logits = (unsigned short*)d_ws;                 // BT*VOCAB bf16
    unsigned short* t_logits = s_logits + (size_t)BT * VOCAB;         // BT*VOCAB bf16
    float* row_sums = (float*)(t_logits + (size_t)BT * VOCAB);        // BT f32

    dim3 grid(BT / BM, VOCAB / BN);   // (16, 250); x fastest shares B tile
    gemm_bt_kernel<<<grid, 256, 0, stream>>>(s_in, s_w, s_logits, HS);
    gemm_bt_kernel<<<grid, 256, 0, stream>>>(t_in, t_w, t_logits, HT);
    jsd_row_kernel<<<BT, 256, 0, stream>>>(s_logits, t_logits, row_sums);
    finalize_kernel<<<1, 256, 0, stream>>>(row_sums, lbl, out);
}